// Round 1
// baseline (761.078 us; speedup 1.0000x reference)
//
#include <hip/hip_runtime.h>
#include <hip/hip_bf16.h>
#include <math.h>

#define BB 4
#define SS 1024
#define DD 1024
#define HH 16
#define DHH 64
#define BHH (BB * HH)

#define LDB 88   // bf16 LDS row stride: 176B rows -> 16B aligned, 2-way-max conflicts (free)
#define LDC 68   // fp32 LDS row stride for epilogue staging (272B rows, 16B aligned)

typedef __attribute__((ext_vector_type(8))) short short8;   // 8 x bf16 (4 VGPRs)
typedef __attribute__((ext_vector_type(4))) float f32x4;    // MFMA accumulator

__device__ __forceinline__ unsigned short f2bf(float x) {
  __hip_bfloat16 h = __float2bfloat16(x);
  return *reinterpret_cast<unsigned short*>(&h);
}

// Stage 64x64 bf16 tile, global row-major (ld elems) -> LDS [64][LDB].
__device__ __forceinline__ void stageb(const unsigned short* __restrict__ src, int ld,
                                       unsigned short* __restrict__ dst, int tid) {
#pragma unroll
  for (int u = 0; u < 2; ++u) {
    int cidx = tid + 256 * u;      // 512 chunks of 8 bf16
    int r = cidx >> 3;
    int c8 = (cidx & 7) * 8;
    float4 v = *reinterpret_cast<const float4*>(src + (size_t)r * ld + c8);
    *reinterpret_cast<float4*>(dst + r * LDB + c8) = v;
  }
}

// A/B operand fragment: elem[idx = lane&15][k = kh + (lane>>4)*8 + j], j=0..7
__device__ __forceinline__ short8 ldfrag(const unsigned short* __restrict__ base,
                                         int row16, int kh, int lane) {
  const unsigned short* p = base + (size_t)(row16 + (lane & 15)) * LDB + kh + (lane >> 4) * 8;
  return *reinterpret_cast<const short8*>(p);
}

// 4 waves: wave w computes rows 0..63 x cols [w*16, w*16+16) of a 64x64 tile.
__device__ __forceinline__ void mfma_tile(const unsigned short* As, const unsigned short* Bs,
                                          int w, int lane, f32x4 acc[4]) {
#pragma unroll
  for (int kh = 0; kh < 64; kh += 32) {
    short8 b = ldfrag(Bs, w * 16, kh, lane);
#pragma unroll
    for (int mb = 0; mb < 4; ++mb) {
      short8 a = ldfrag(As, mb * 16, kh, lane);
      acc[mb] = __builtin_amdgcn_mfma_f32_16x16x32_bf16(a, b, acc[mb], 0, 0, 0);
    }
  }
}

// acc -> LDS fp32 [64][LDC] (row = mb*16 + quad*4 + r, col = w*16 + lane&15)
__device__ __forceinline__ void acc_to_lds(float* Cs, const f32x4 acc[4], int w, int lane,
                                           float scale) {
  int quad = lane >> 4, col = w * 16 + (lane & 15);
#pragma unroll
  for (int mb = 0; mb < 4; ++mb)
#pragma unroll
    for (int r = 0; r < 4; ++r)
      Cs[(mb * 16 + quad * 4 + r) * LDC + col] = acc[mb][r] * scale;
}

// ---- K0a: fp32 -> bf16 elementwise
__global__ __launch_bounds__(256) void cvt_kernel(const float* __restrict__ in,
                                                  unsigned short* __restrict__ out, int n4) {
  int i = blockIdx.x * 256 + threadIdx.x;
  if (i < n4) {
    float4 v = reinterpret_cast<const float4*>(in)[i];
    ushort4 o;
    o.x = f2bf(v.x); o.y = f2bf(v.y); o.z = f2bf(v.z); o.w = f2bf(v.w);
    reinterpret_cast<ushort4*>(out)[i] = o;
  }
}

// ---- K0b: v (B,S,H,DH) -> vT bf16 [bh][d][s]
__global__ __launch_bounds__(256) void vtrans_kernel(const float* __restrict__ v,
                                                     unsigned short* __restrict__ vT) {
  __shared__ unsigned short T[64 * LDC];
  int tid = threadIdx.x;
  int s0 = blockIdx.x * 64, bh = blockIdx.y;
  int b = bh >> 4, h = bh & 15;
#pragma unroll
  for (int u = 0; u < 4; ++u) {
    int f = tid + 256 * u;
    int r = f >> 4, c4 = (f & 15) * 4;
    float4 vv = *reinterpret_cast<const float4*>(v + ((size_t)(b * SS + s0 + r)) * DD + h * DHH + c4);
    T[(c4 + 0) * LDC + r] = f2bf(vv.x);
    T[(c4 + 1) * LDC + r] = f2bf(vv.y);
    T[(c4 + 2) * LDC + r] = f2bf(vv.z);
    T[(c4 + 3) * LDC + r] = f2bf(vv.w);
  }
  __syncthreads();
#pragma unroll
  for (int u = 0; u < 4; ++u) {
    int f = tid + 256 * u;
    int d = f >> 4, s4 = (f & 15) * 4;
    ushort4 o = *reinterpret_cast<const ushort4*>(&T[d * LDC + s4]);
    *reinterpret_cast<ushort4*>(vT + ((size_t)(bh * DHH + d)) * SS + s0 + s4) = o;
  }
}

// ---- K1 (fused): flash-style attention per (qt, bh) 64-row tile.
//   For each of 16 K-tiles: QK^T/8 + c*scores + mask -> att (global, unchanged math),
//   online softmax (running m/l in LDS), P built in LDS, O += P@V via MFMA.
// Eliminates: att re-read (256 MB), pmax/psum round-trip, second 64M exp pass.
__global__ __launch_bounds__(256) void attn_fused_kernel(
    const unsigned short* __restrict__ qb, const unsigned short* __restrict__ kb,
    const unsigned short* __restrict__ vT, const float* __restrict__ scores,
    const float* __restrict__ mask, const float* __restrict__ c,
    float* __restrict__ att, unsigned short* __restrict__ ctxb) {
  __shared__ unsigned short Ps[64 * LDB];  // Q staging at start, then P tiles
  __shared__ unsigned short Ks[64 * LDB];
  __shared__ unsigned short Vs[64 * LDB];
  __shared__ float Cs[64 * LDC];           // fp32 QK tile for epilogue / final ctx
  __shared__ float mrun[64], lrun[64], ascale[64];
  int tid = threadIdx.x, lane = tid & 63, w = tid >> 6;
  int qt = blockIdx.x, bh = blockIdx.y;
  int b = bh >> 4, h = bh & 15;
  int qr0 = qt * 64;

  stageb(qb + ((size_t)(b * SS + qr0)) * DD + h * DHH, DD, Ps, tid);
  if (tid < 64) { mrun[tid] = -3.0e38f; lrun[tid] = 0.0f; }
  __syncthreads();

  // Hoist Q fragments to registers (frees Ps region for P tiles)
  short8 qa[2][4];
#pragma unroll
  for (int kh = 0; kh < 2; ++kh)
#pragma unroll
    for (int mb = 0; mb < 4; ++mb)
      qa[kh][mb] = ldfrag(Ps, mb * 16, kh * 32, lane);

  float cc = c[0];
  f32x4 accO[4] = {};

  for (int kt = 0; kt < 16; ++kt) {
    int kr0 = kt * 64;
    stageb(kb + ((size_t)(b * SS + kr0)) * DD + h * DHH, DD, Ks, tid);
    stageb(vT + (size_t)bh * DHH * SS + kr0, SS, Vs, tid);
    __syncthreads();  // S1: K/V staged (also covers qa ds_reads before Ps overwrite)

    f32x4 acc[4] = {};
#pragma unroll
    for (int kh = 0; kh < 2; ++kh) {
      short8 bfr = ldfrag(Ks, w * 16, kh * 32, lane);
#pragma unroll
      for (int mb = 0; mb < 4; ++mb)
        acc[mb] = __builtin_amdgcn_mfma_f32_16x16x32_bf16(qa[kh][mb], bfr, acc[mb], 0, 0, 0);
    }
    acc_to_lds(Cs, acc, w, lane, 0.125f);
    __syncthreads();  // S2: Cs complete

    // Epilogue: att write (identical math to previous K1) + online-softmax update + P build
#pragma unroll
    for (int u = 0; u < 4; ++u) {
      int f = tid + 256 * u;
      int row = f >> 4, c4 = (f & 15) * 4;
      int rg = bh * SS + qr0 + row;
      size_t goff = (size_t)rg * SS + kr0 + c4;
      float4 qk = *reinterpret_cast<const float4*>(&Cs[row * LDC + c4]);
      float4 sc = *reinterpret_cast<const float4*>(scores + goff);
      float4 mv = *reinterpret_cast<const float4*>(mask + b * SS + kr0 + c4);
      float o0 = qk.x + cc * sc.x - 1e8f * (1.0f - mv.x);
      float o1 = qk.y + cc * sc.y - 1e8f * (1.0f - mv.y);
      float o2 = qk.z + cc * sc.z - 1e8f * (1.0f - mv.z);
      float o3 = qk.w + cc * sc.w - 1e8f * (1.0f - mv.w);
      float4 ov = {o0, o1, o2, o3};
      *reinterpret_cast<float4*>(att + goff) = ov;
      float m = fmaxf(fmaxf(o0, o1), fmaxf(o2, o3));
#pragma unroll
      for (int off = 1; off <= 8; off <<= 1) m = fmaxf(m, __shfl_xor(m, off));
      float mo = mrun[row];            // broadcast read (row group = 16 lanes, same wave)
      float mn = fmaxf(mo, m);
      float e0 = __expf(o0 - mn), e1 = __expf(o1 - mn);
      float e2 = __expf(o2 - mn), e3 = __expf(o3 - mn);
      float l = e0 + e1 + e2 + e3;
#pragma unroll
      for (int off = 1; off <= 8; off <<= 1) l += __shfl_xor(l, off);
      ushort4 pv;
      pv.x = f2bf(e0); pv.y = f2bf(e1); pv.z = f2bf(e2); pv.w = f2bf(e3);
      *reinterpret_cast<ushort4*>(&Ps[row * LDB + c4]) = pv;
      if ((tid & 15) == 0) {           // single writer per row; lockstep-safe within wave
        float a = __expf(mo - mn);     // first tile: exp(-3e38-mn)=0, accO starts at 0
        lrun[row] = lrun[row] * a + l;
        mrun[row] = mn;
        ascale[row] = a;
      }
    }
    __syncthreads();  // S3: Ps + ascale visible

    // Rescale O accumulator (row = mb*16 + quad*4 + r, matches acc layout)
#pragma unroll
    for (int mb = 0; mb < 4; ++mb) {
      int rb = mb * 16 + (lane >> 4) * 4;
      accO[mb][0] *= ascale[rb + 0];
      accO[mb][1] *= ascale[rb + 1];
      accO[mb][2] *= ascale[rb + 2];
      accO[mb][3] *= ascale[rb + 3];
    }
    mfma_tile(Ps, Vs, w, lane, accO);
    __syncthreads();  // S4: Ps/Vs reads done before next stage overwrites
  }

  // Final normalization by running denominator
#pragma unroll
  for (int mb = 0; mb < 4; ++mb) {
    int rb = mb * 16 + (lane >> 4) * 4;
    accO[mb][0] *= 1.0f / lrun[rb + 0];
    accO[mb][1] *= 1.0f / lrun[rb + 1];
    accO[mb][2] *= 1.0f / lrun[rb + 2];
    accO[mb][3] *= 1.0f / lrun[rb + 3];
  }
  acc_to_lds(Cs, accO, w, lane, 1.0f);
  __syncthreads();
#pragma unroll
  for (int u = 0; u < 4; ++u) {
    int f = tid + 256 * u;
    int row = f >> 4, c4 = (f & 15) * 4;
    float4 vv = *reinterpret_cast<const float4*>(&Cs[row * LDC + c4]);
    ushort4 o;
    o.x = f2bf(vv.x); o.y = f2bf(vv.y); o.z = f2bf(vv.z); o.w = f2bf(vv.w);
    *reinterpret_cast<ushort4*>(ctxb + ((size_t)(b * SS + qr0 + row)) * DD + h * DHH + c4) = o;
  }
}

// ---- K4: xb = ctxb @ Wp^T (bf16 in/out)
__global__ __launch_bounds__(256) void proj_mfma_kernel(
    const unsigned short* __restrict__ A, const unsigned short* __restrict__ W,
    unsigned short* __restrict__ X) {
  __shared__ unsigned short smem[2 * 64 * LDB];
  unsigned short* As = smem;
  unsigned short* Bs = smem + 64 * LDB;
  float* Cs = reinterpret_cast<float*>(smem);
  int tid = threadIdx.x, lane = tid & 63, w = tid >> 6;
  int d0 = blockIdx.x * 64, n0 = blockIdx.y * 64;
  f32x4 acc[4] = {};
  for (int kc = 0; kc < DD; kc += 64) {
    stageb(A + (size_t)n0 * DD + kc, DD, As, tid);
    stageb(W + (size_t)d0 * DD + kc, DD, Bs, tid);
    __syncthreads();
    mfma_tile(As, Bs, w, lane, acc);
    __syncthreads();
  }
  acc_to_lds(Cs, acc, w, lane, 1.0f);
  __syncthreads();
#pragma unroll
  for (int u = 0; u < 4; ++u) {
    int f = tid + 256 * u;
    int row = f >> 4, c4 = (f & 15) * 4;
    float4 vv = *reinterpret_cast<const float4*>(&Cs[row * LDC + c4]);
    ushort4 o;
    o.x = f2bf(vv.x); o.y = f2bf(vv.y); o.z = f2bf(vv.z); o.w = f2bf(vv.w);
    *reinterpret_cast<ushort4*>(X + (size_t)(n0 + row) * DD + d0 + c4) = o;
  }
}

// ---- K5: y = [q | x] @ Wm^T (K=2048), fp32 out
__global__ __launch_bounds__(256) void minus_mfma_kernel(
    const unsigned short* __restrict__ qb, const unsigned short* __restrict__ xb,
    const unsigned short* __restrict__ Wm, float* __restrict__ Y) {
  __shared__ unsigned short smem[2 * 64 * LDB];
  unsigned short* As = smem;
  unsigned short* Bs = smem + 64 * LDB;
  float* Cs = reinterpret_cast<float*>(smem);
  int tid = threadIdx.x, lane = tid & 63, w = tid >> 6;
  int d0 = blockIdx.x * 64, n0 = blockIdx.y * 64;
  f32x4 acc[4] = {};
  for (int kc = 0; kc < 2 * DD; kc += 64) {
    const unsigned short* asrc = (kc < DD) ? (qb + (size_t)n0 * DD + kc)
                                           : (xb + (size_t)n0 * DD + (kc - DD));
    stageb(asrc, DD, As, tid);
    stageb(Wm + (size_t)d0 * (2 * DD) + kc, 2 * DD, Bs, tid);
    __syncthreads();
    mfma_tile(As, Bs, w, lane, acc);
    __syncthreads();
  }
  acc_to_lds(Cs, acc, w, lane, 1.0f);
  __syncthreads();
#pragma unroll
  for (int u = 0; u < 4; ++u) {
    int f = tid + 256 * u;
    int row = f >> 4, c4 = (f & 15) * 4;
    float4 vv = *reinterpret_cast<const float4*>(&Cs[row * LDC + c4]);
    *reinterpret_cast<float4*>(Y + (size_t)(n0 + row) * DD + d0 + c4) = vv;
  }
}

// ---- K6: in-place LayerNorm over last dim (1024)
__global__ __launch_bounds__(256) void ln_kernel(
    float* __restrict__ Y, const float* __restrict__ w, const float* __restrict__ b) {
  __shared__ float ps[4], ps2[4];
  int row = blockIdx.x, t = threadIdx.x;
  float* rp = Y + (size_t)row * DD;
  float4 v = *reinterpret_cast<const float4*>(rp + t * 4);
  float s = v.x + v.y + v.z + v.w;
  float s2 = v.x * v.x + v.y * v.y + v.z * v.z + v.w * v.w;
#pragma unroll
  for (int o = 32; o > 0; o >>= 1) {
    s += __shfl_down(s, o);
    s2 += __shfl_down(s2, o);
  }
  if ((t & 63) == 0) { ps[t >> 6] = s; ps2[t >> 6] = s2; }
  __syncthreads();
  s = ps[0] + ps[1] + ps[2] + ps[3];
  s2 = ps2[0] + ps2[1] + ps2[2] + ps2[3];
  float mu = s * (1.0f / DD);
  float var = s2 * (1.0f / DD) - mu * mu;
  float rs = rsqrtf(var + 1e-5f);
  float4 wv = *reinterpret_cast<const float4*>(w + t * 4);
  float4 bv = *reinterpret_cast<const float4*>(b + t * 4);
  float4 ov;
  ov.x = (v.x - mu) * rs * wv.x + bv.x;
  ov.y = (v.y - mu) * rs * wv.y + bv.y;
  ov.z = (v.z - mu) * rs * wv.z + bv.z;
  ov.w = (v.w - mu) * rs * wv.w + bv.w;
  *reinterpret_cast<float4*>(rp + t * 4) = ov;
}

extern "C" void kernel_launch(void* const* d_in, const int* in_sizes, int n_in,
                              void* d_out, int out_size, void* d_ws, size_t ws_size,
                              hipStream_t stream) {
  const float* q      = (const float*)d_in[0];
  const float* k      = (const float*)d_in[1];
  const float* v      = (const float*)d_in[2];
  const float* mask   = (const float*)d_in[3];
  const float* scores = (const float*)d_in[4];
  const float* W_proj = (const float*)d_in[5];
  const float* W_minus= (const float*)d_in[6];
  const float* ln_w   = (const float*)d_in[7];
  const float* ln_b   = (const float*)d_in[8];
  const float* c      = (const float*)d_in[9];

  float* y   = (float*)d_out;             // (B,S,D)
  float* att = y + (size_t)BB * SS * DD;  // (B,H,S,S)

  const size_t MB = 1u << 20;
  char* w = (char*)d_ws;
  unsigned short* qb   = (unsigned short*)(w);             // 8 MB
  unsigned short* kb   = (unsigned short*)(w + 8 * MB);    // 8 MB
  unsigned short* vT   = (unsigned short*)(w + 16 * MB);   // 8 MB
  unsigned short* Wpb  = (unsigned short*)(w + 24 * MB);   // 2 MB
  unsigned short* Wmb  = (unsigned short*)(w + 26 * MB);   // 4 MB
  unsigned short* ctxb = (unsigned short*)(w + 30 * MB);   // 8 MB
  unsigned short* xb   = (unsigned short*)(w + 38 * MB);   // 8 MB

  const int NQ = BB * SS * DD;  // 4M
  cvt_kernel<<<dim3(NQ / 4 / 256), 256, 0, stream>>>(q, qb, NQ / 4);
  cvt_kernel<<<dim3(NQ / 4 / 256), 256, 0, stream>>>(k, kb, NQ / 4);
  cvt_kernel<<<dim3(DD * DD / 4 / 256), 256, 0, stream>>>(W_proj, Wpb, DD * DD / 4);
  cvt_kernel<<<dim3(2 * DD * DD / 4 / 256), 256, 0, stream>>>(W_minus, Wmb, 2 * DD * DD / 4);
  vtrans_kernel<<<dim3(16, BHH), 256, 0, stream>>>(v, vT);

  attn_fused_kernel<<<dim3(16, BHH), 256, 0, stream>>>(qb, kb, vT, scores, mask, c, att, ctxb);
  proj_mfma_kernel<<<dim3(16, 64), 256, 0, stream>>>(ctxb, Wpb, xb);
  minus_mfma_kernel<<<dim3(16, 64), 256, 0, stream>>>(qb, xb, Wmb, y);
  ln_kernel<<<dim3(BB * SS), 256, 0, stream>>>(y, ln_w, ln_b);
}

// Round 2
// 676.153 us; speedup vs baseline: 1.1256x; 1.1256x over previous
//
#include <hip/hip_runtime.h>
#include <hip/hip_bf16.h>
#include <math.h>

#define BB 4
#define SS 1024
#define DD 1024
#define HH 16
#define DHH 64
#define BHH (BB * HH)

#define LDB 88   // bf16 LDS row stride: 176B rows -> 16B aligned, 2-way-max conflicts (free)
#define LDC 68   // fp32 LDS row stride for epilogue staging (272B rows, 16B aligned)

typedef __attribute__((ext_vector_type(8))) short short8;   // 8 x bf16 (4 VGPRs)
typedef __attribute__((ext_vector_type(4))) float f32x4;    // MFMA accumulator

__device__ __forceinline__ unsigned short f2bf(float x) {
  __hip_bfloat16 h = __float2bfloat16(x);
  return *reinterpret_cast<unsigned short*>(&h);
}

// Stage 64x64 bf16 tile, global row-major (ld elems) -> LDS [64][LDB].
__device__ __forceinline__ void stageb(const unsigned short* __restrict__ src, int ld,
                                       unsigned short* __restrict__ dst, int tid) {
#pragma unroll
  for (int u = 0; u < 2; ++u) {
    int cidx = tid + 256 * u;      // 512 chunks of 8 bf16
    int r = cidx >> 3;
    int c8 = (cidx & 7) * 8;
    float4 v = *reinterpret_cast<const float4*>(src + (size_t)r * ld + c8);
    *reinterpret_cast<float4*>(dst + r * LDB + c8) = v;
  }
}

// A/B operand fragment: elem[idx = lane&15][k = kh + (lane>>4)*8 + j], j=0..7
__device__ __forceinline__ short8 ldfrag(const unsigned short* __restrict__ base,
                                         int row16, int kh, int lane) {
  const unsigned short* p = base + (size_t)(row16 + (lane & 15)) * LDB + kh + (lane >> 4) * 8;
  return *reinterpret_cast<const short8*>(p);
}

// 4 waves: wave w computes rows 0..63 x cols [w*16, w*16+16) of a 64x64 tile.
__device__ __forceinline__ void mfma_tile(const unsigned short* As, const unsigned short* Bs,
                                          int w, int lane, f32x4 acc[4]) {
#pragma unroll
  for (int kh = 0; kh < 64; kh += 32) {
    short8 b = ldfrag(Bs, w * 16, kh, lane);
#pragma unroll
    for (int mb = 0; mb < 4; ++mb) {
      short8 a = ldfrag(As, mb * 16, kh, lane);
      acc[mb] = __builtin_amdgcn_mfma_f32_16x16x32_bf16(a, b, acc[mb], 0, 0, 0);
    }
  }
}

// acc -> LDS fp32 [64][LDC] (row = mb*16 + quad*4 + r, col = w*16 + lane&15)
__device__ __forceinline__ void acc_to_lds(float* Cs, const f32x4 acc[4], int w, int lane,
                                           float scale) {
  int quad = lane >> 4, col = w * 16 + (lane & 15);
#pragma unroll
  for (int mb = 0; mb < 4; ++mb)
#pragma unroll
    for (int r = 0; r < 4; ++r)
      Cs[(mb * 16 + quad * 4 + r) * LDC + col] = acc[mb][r] * scale;
}

// ---- K0a: fp32 -> bf16 elementwise
__global__ __launch_bounds__(256) void cvt_kernel(const float* __restrict__ in,
                                                  unsigned short* __restrict__ out, int n4) {
  int i = blockIdx.x * 256 + threadIdx.x;
  if (i < n4) {
    float4 v = reinterpret_cast<const float4*>(in)[i];
    ushort4 o;
    o.x = f2bf(v.x); o.y = f2bf(v.y); o.z = f2bf(v.z); o.w = f2bf(v.w);
    reinterpret_cast<ushort4*>(out)[i] = o;
  }
}

// ---- K0b: v (B,S,H,DH) -> vT bf16 [bh][d][s]
__global__ __launch_bounds__(256) void vtrans_kernel(const float* __restrict__ v,
                                                     unsigned short* __restrict__ vT) {
  __shared__ unsigned short T[64 * LDC];
  int tid = threadIdx.x;
  int s0 = blockIdx.x * 64, bh = blockIdx.y;
  int b = bh >> 4, h = bh & 15;
#pragma unroll
  for (int u = 0; u < 4; ++u) {
    int f = tid + 256 * u;
    int r = f >> 4, c4 = (f & 15) * 4;
    float4 vv = *reinterpret_cast<const float4*>(v + ((size_t)(b * SS + s0 + r)) * DD + h * DHH + c4);
    T[(c4 + 0) * LDC + r] = f2bf(vv.x);
    T[(c4 + 1) * LDC + r] = f2bf(vv.y);
    T[(c4 + 2) * LDC + r] = f2bf(vv.z);
    T[(c4 + 3) * LDC + r] = f2bf(vv.w);
  }
  __syncthreads();
#pragma unroll
  for (int u = 0; u < 4; ++u) {
    int f = tid + 256 * u;
    int d = f >> 4, s4 = (f & 15) * 4;
    ushort4 o = *reinterpret_cast<const ushort4*>(&T[d * LDC + s4]);
    *reinterpret_cast<ushort4*>(vT + ((size_t)(bh * DHH + d)) * SS + s0 + s4) = o;
  }
}

// ---- K1 (fused, pipelined): flash-style attention per (qt, bh) 64-row tile.
//   All global loads are register-prefetched one kt-tile ahead so HBM latency
//   hides under the MFMA/epilogue phases instead of sitting between barriers.
//   XCD swizzle: each XCD owns 8 bh (K/V panels 2 MB -> L2-resident).
__global__ __launch_bounds__(256) void attn_fused_kernel(
    const unsigned short* __restrict__ qb, const unsigned short* __restrict__ kb,
    const unsigned short* __restrict__ vT, const float* __restrict__ scores,
    const float* __restrict__ mask, const float* __restrict__ c,
    float* __restrict__ att, unsigned short* __restrict__ ctxb) {
  __shared__ unsigned short Ps[64 * LDB];  // Q staging at start, then P tiles
  __shared__ unsigned short Ks[64 * LDB];
  __shared__ unsigned short Vs[64 * LDB];
  __shared__ float Cs[64 * LDC];           // fp32 QK tile for epilogue / final ctx
  __shared__ float mrun[64], lrun[64], ascale[64];
  int tid = threadIdx.x, lane = tid & 63, w = tid >> 6;

  // XCD-aware swizzle: flat id -> (bh, qt) such that XCD x (= flat%8, round-robin
  // dispatch heuristic) owns bh in [x*8, x*8+8). Perf-only; any mapping is correct.
  int flat = blockIdx.x + 16 * blockIdx.y;
  int bh = (flat & 7) * 8 + ((flat >> 3) & 7);
  int qt = flat >> 6;
  int b = bh >> 4, h = bh & 15;
  int qr0 = qt * 64;

  // per-thread staging coords (2 chunks of 8 bf16 per thread per tile)
  int r0 = tid >> 3, c80 = (tid & 7) * 8;
  int r1 = r0 + 32;
  const unsigned short* kB = kb + (size_t)b * SS * DD + h * DHH;
  const unsigned short* vB = vT + (size_t)bh * DHH * SS;
  unsigned short* KsW0 = Ks + r0 * LDB + c80;
  unsigned short* KsW1 = Ks + r1 * LDB + c80;
  unsigned short* VsW0 = Vs + r0 * LDB + c80;
  unsigned short* VsW1 = Vs + r1 * LDB + c80;

  // epilogue coords: thread handles rows rowe+16*u2, cols [c4, c4+4)
  int rowe = tid >> 4;
  int c4 = (tid & 15) * 4;
  size_t eOff = ((size_t)(bh * SS + qr0 + rowe)) * SS + c4;  // + u2*16*SS + kr0
  size_t mkOff = (size_t)b * SS + c4;                        // + kr0

  // ---- prologue: stage Q + K/V tile 0 to LDS, issue scores/mask tile 0 to regs
  stageb(qb + ((size_t)(b * SS + qr0)) * DD + h * DHH, DD, Ps, tid);
  {
    float4 k0 = *reinterpret_cast<const float4*>(kB + (size_t)r0 * DD + c80);
    float4 k1 = *reinterpret_cast<const float4*>(kB + (size_t)r1 * DD + c80);
    float4 v0 = *reinterpret_cast<const float4*>(vB + (size_t)r0 * SS + c80);
    float4 v1 = *reinterpret_cast<const float4*>(vB + (size_t)r1 * SS + c80);
    *reinterpret_cast<float4*>(KsW0) = k0;
    *reinterpret_cast<float4*>(KsW1) = k1;
    *reinterpret_cast<float4*>(VsW0) = v0;
    *reinterpret_cast<float4*>(VsW1) = v1;
  }
  if (tid < 64) { mrun[tid] = -3.0e38f; lrun[tid] = 0.0f; }

  float4 sc[4];
#pragma unroll
  for (int u2 = 0; u2 < 4; ++u2)
    sc[u2] = *reinterpret_cast<const float4*>(scores + eOff + (size_t)u2 * 16 * SS);
  float4 mk = *reinterpret_cast<const float4*>(mask + mkOff);

  __syncthreads();  // prologue publish (Ps/Ks/Vs/stats)

  // Hoist Q fragments to registers (frees Ps region for P tiles)
  short8 qa[2][4];
#pragma unroll
  for (int kh = 0; kh < 2; ++kh)
#pragma unroll
    for (int mb = 0; mb < 4; ++mb)
      qa[kh][mb] = ldfrag(Ps, mb * 16, kh * 32, lane);

  float cc = c[0];
  f32x4 accO[4] = {};

  for (int kt = 0; kt < 16; ++kt) {
    int kr0 = kt * 64;
    // Issue next K/V tile into registers; LDS write happens after S4.
    float4 kn0 = {}, kn1 = {}, vn0 = {}, vn1 = {};
    if (kt < 15) {
      int kr = kr0 + 64;
      kn0 = *reinterpret_cast<const float4*>(kB + (size_t)(kr + r0) * DD + c80);
      kn1 = *reinterpret_cast<const float4*>(kB + (size_t)(kr + r1) * DD + c80);
      vn0 = *reinterpret_cast<const float4*>(vB + (size_t)r0 * SS + kr + c80);
      vn1 = *reinterpret_cast<const float4*>(vB + (size_t)r1 * SS + kr + c80);
    }

    // QK^T from LDS-resident K tile
    f32x4 acc[4] = {};
    __builtin_amdgcn_s_setprio(1);
#pragma unroll
    for (int kh = 0; kh < 2; ++kh) {
      short8 bfr = ldfrag(Ks, w * 16, kh * 32, lane);
#pragma unroll
      for (int mb = 0; mb < 4; ++mb)
        acc[mb] = __builtin_amdgcn_mfma_f32_16x16x32_bf16(qa[kh][mb], bfr, acc[mb], 0, 0, 0);
    }
    __builtin_amdgcn_s_setprio(0);
    acc_to_lds(Cs, acc, w, lane, 0.125f);
    __syncthreads();  // S2: Cs complete

    // Epilogue: att write (unchanged math) + online-softmax update + P build.
    // scores/mask already in registers (prefetched last iteration).
#pragma unroll
    for (int u2 = 0; u2 < 4; ++u2) {
      int row = rowe + 16 * u2;
      float4 qk = *reinterpret_cast<const float4*>(&Cs[row * LDC + c4]);
      float o0 = qk.x + cc * sc[u2].x - 1e8f * (1.0f - mk.x);
      float o1 = qk.y + cc * sc[u2].y - 1e8f * (1.0f - mk.y);
      float o2 = qk.z + cc * sc[u2].z - 1e8f * (1.0f - mk.z);
      float o3 = qk.w + cc * sc[u2].w - 1e8f * (1.0f - mk.w);
      float4 ov = {o0, o1, o2, o3};
      *reinterpret_cast<float4*>(att + eOff + (size_t)u2 * 16 * SS + kr0) = ov;
      float m = fmaxf(fmaxf(o0, o1), fmaxf(o2, o3));
#pragma unroll
      for (int off = 1; off <= 8; off <<= 1) m = fmaxf(m, __shfl_xor(m, off));
      float mo = mrun[row];            // broadcast read within 16-lane row group
      float mn = fmaxf(mo, m);
      float e0 = __expf(o0 - mn), e1 = __expf(o1 - mn);
      float e2 = __expf(o2 - mn), e3 = __expf(o3 - mn);
      float l = e0 + e1 + e2 + e3;
#pragma unroll
      for (int off = 1; off <= 8; off <<= 1) l += __shfl_xor(l, off);
      ushort4 pv;
      pv.x = f2bf(e0); pv.y = f2bf(e1); pv.z = f2bf(e2); pv.w = f2bf(e3);
      *reinterpret_cast<ushort4*>(&Ps[row * LDB + c4]) = pv;
      if ((tid & 15) == 0) {           // single writer per row
        float a = __expf(mo - mn);     // first tile: exp(-inf)=0, accO starts at 0
        lrun[row] = lrun[row] * a + l;
        mrun[row] = mn;
        ascale[row] = a;
      }
    }
    // Issue next tile's scores/mask now that current regs are consumed.
    if (kt < 15) {
#pragma unroll
      for (int u2 = 0; u2 < 4; ++u2)
        sc[u2] = *reinterpret_cast<const float4*>(scores + eOff + (size_t)u2 * 16 * SS + kr0 + 64);
      mk = *reinterpret_cast<const float4*>(mask + mkOff + kr0 + 64);
    }
    __syncthreads();  // S3: Ps + ascale visible

    // Rescale O accumulator (row = mb*16 + quad*4 + r, matches acc layout)
#pragma unroll
    for (int mb = 0; mb < 4; ++mb) {
      int rb = mb * 16 + (lane >> 4) * 4;
      accO[mb][0] *= ascale[rb + 0];
      accO[mb][1] *= ascale[rb + 1];
      accO[mb][2] *= ascale[rb + 2];
      accO[mb][3] *= ascale[rb + 3];
    }
    __builtin_amdgcn_s_setprio(1);
    mfma_tile(Ps, Vs, w, lane, accO);
    __builtin_amdgcn_s_setprio(0);
    __syncthreads();  // S4: PV reads of Ps/Vs done
    if (kt < 15) {
      *reinterpret_cast<float4*>(KsW0) = kn0;
      *reinterpret_cast<float4*>(KsW1) = kn1;
      *reinterpret_cast<float4*>(VsW0) = vn0;
      *reinterpret_cast<float4*>(VsW1) = vn1;
      __syncthreads();  // S1: next tile's K/V published
    }
  }

  // Final normalization by running denominator
#pragma unroll
  for (int mb = 0; mb < 4; ++mb) {
    int rb = mb * 16 + (lane >> 4) * 4;
    accO[mb][0] *= 1.0f / lrun[rb + 0];
    accO[mb][1] *= 1.0f / lrun[rb + 1];
    accO[mb][2] *= 1.0f / lrun[rb + 2];
    accO[mb][3] *= 1.0f / lrun[rb + 3];
  }
  acc_to_lds(Cs, accO, w, lane, 1.0f);
  __syncthreads();
#pragma unroll
  for (int u = 0; u < 4; ++u) {
    int f = tid + 256 * u;
    int row = f >> 4, cc4 = (f & 15) * 4;
    float4 vv = *reinterpret_cast<const float4*>(&Cs[row * LDC + cc4]);
    ushort4 o;
    o.x = f2bf(vv.x); o.y = f2bf(vv.y); o.z = f2bf(vv.z); o.w = f2bf(vv.w);
    *reinterpret_cast<ushort4*>(ctxb + ((size_t)(b * SS + qr0 + row)) * DD + h * DHH + cc4) = o;
  }
}

// ---- K4: xb = ctxb @ Wp^T (bf16 in/out)
__global__ __launch_bounds__(256) void proj_mfma_kernel(
    const unsigned short* __restrict__ A, const unsigned short* __restrict__ W,
    unsigned short* __restrict__ X) {
  __shared__ unsigned short smem[2 * 64 * LDB];
  unsigned short* As = smem;
  unsigned short* Bs = smem + 64 * LDB;
  float* Cs = reinterpret_cast<float*>(smem);
  int tid = threadIdx.x, lane = tid & 63, w = tid >> 6;
  int d0 = blockIdx.x * 64, n0 = blockIdx.y * 64;
  f32x4 acc[4] = {};
  for (int kc = 0; kc < DD; kc += 64) {
    stageb(A + (size_t)n0 * DD + kc, DD, As, tid);
    stageb(W + (size_t)d0 * DD + kc, DD, Bs, tid);
    __syncthreads();
    mfma_tile(As, Bs, w, lane, acc);
    __syncthreads();
  }
  acc_to_lds(Cs, acc, w, lane, 1.0f);
  __syncthreads();
#pragma unroll
  for (int u = 0; u < 4; ++u) {
    int f = tid + 256 * u;
    int row = f >> 4, c4 = (f & 15) * 4;
    float4 vv = *reinterpret_cast<const float4*>(&Cs[row * LDC + c4]);
    ushort4 o;
    o.x = f2bf(vv.x); o.y = f2bf(vv.y); o.z = f2bf(vv.z); o.w = f2bf(vv.w);
    *reinterpret_cast<ushort4*>(X + (size_t)(n0 + row) * DD + d0 + c4) = o;
  }
}

// ---- K5: y = [q | x] @ Wm^T (K=2048), fp32 out
__global__ __launch_bounds__(256) void minus_mfma_kernel(
    const unsigned short* __restrict__ qb, const unsigned short* __restrict__ xb,
    const unsigned short* __restrict__ Wm, float* __restrict__ Y) {
  __shared__ unsigned short smem[2 * 64 * LDB];
  unsigned short* As = smem;
  unsigned short* Bs = smem + 64 * LDB;
  float* Cs = reinterpret_cast<float*>(smem);
  int tid = threadIdx.x, lane = tid & 63, w = tid >> 6;
  int d0 = blockIdx.x * 64, n0 = blockIdx.y * 64;
  f32x4 acc[4] = {};
  for (int kc = 0; kc < 2 * DD; kc += 64) {
    const unsigned short* asrc = (kc < DD) ? (qb + (size_t)n0 * DD + kc)
                                           : (xb + (size_t)n0 * DD + (kc - DD));
    stageb(asrc, DD, As, tid);
    stageb(Wm + (size_t)d0 * (2 * DD) + kc, 2 * DD, Bs, tid);
    __syncthreads();
    mfma_tile(As, Bs, w, lane, acc);
    __syncthreads();
  }
  acc_to_lds(Cs, acc, w, lane, 1.0f);
  __syncthreads();
#pragma unroll
  for (int u = 0; u < 4; ++u) {
    int f = tid + 256 * u;
    int row = f >> 4, c4 = (f & 15) * 4;
    float4 vv = *reinterpret_cast<const float4*>(&Cs[row * LDC + c4]);
    *reinterpret_cast<float4*>(Y + (size_t)(n0 + row) * DD + d0 + c4) = vv;
  }
}

// ---- K6: in-place LayerNorm over last dim (1024)
__global__ __launch_bounds__(256) void ln_kernel(
    float* __restrict__ Y, const float* __restrict__ w, const float* __restrict__ b) {
  __shared__ float ps[4], ps2[4];
  int row = blockIdx.x, t = threadIdx.x;
  float* rp = Y + (size_t)row * DD;
  float4 v = *reinterpret_cast<const float4*>(rp + t * 4);
  float s = v.x + v.y + v.z + v.w;
  float s2 = v.x * v.x + v.y * v.y + v.z * v.z + v.w * v.w;
#pragma unroll
  for (int o = 32; o > 0; o >>= 1) {
    s += __shfl_down(s, o);
    s2 += __shfl_down(s2, o);
  }
  if ((t & 63) == 0) { ps[t >> 6] = s; ps2[t >> 6] = s2; }
  __syncthreads();
  s = ps[0] + ps[1] + ps[2] + ps[3];
  s2 = ps2[0] + ps2[1] + ps2[2] + ps2[3];
  float mu = s * (1.0f / DD);
  float var = s2 * (1.0f / DD) - mu * mu;
  float rs = rsqrtf(var + 1e-5f);
  float4 wv = *reinterpret_cast<const float4*>(w + t * 4);
  float4 bv = *reinterpret_cast<const float4*>(b + t * 4);
  float4 ov;
  ov.x = (v.x - mu) * rs * wv.x + bv.x;
  ov.y = (v.y - mu) * rs * wv.y + bv.y;
  ov.z = (v.z - mu) * rs * wv.z + bv.z;
  ov.w = (v.w - mu) * rs * wv.w + bv.w;
  *reinterpret_cast<float4*>(rp + t * 4) = ov;
}

extern "C" void kernel_launch(void* const* d_in, const int* in_sizes, int n_in,
                              void* d_out, int out_size, void* d_ws, size_t ws_size,
                              hipStream_t stream) {
  const float* q      = (const float*)d_in[0];
  const float* k      = (const float*)d_in[1];
  const float* v      = (const float*)d_in[2];
  const float* mask   = (const float*)d_in[3];
  const float* scores = (const float*)d_in[4];
  const float* W_proj = (const float*)d_in[5];
  const float* W_minus= (const float*)d_in[6];
  const float* ln_w   = (const float*)d_in[7];
  const float* ln_b   = (const float*)d_in[8];
  const float* c      = (const float*)d_in[9];

  float* y   = (float*)d_out;             // (B,S,D)
  float* att = y + (size_t)BB * SS * DD;  // (B,H,S,S)

  const size_t MB = 1u << 20;
  char* w = (char*)d_ws;
  unsigned short* qb   = (unsigned short*)(w);             // 8 MB
  unsigned short* kb   = (unsigned short*)(w + 8 * MB);    // 8 MB
  unsigned short* vT   = (unsigned short*)(w + 16 * MB);   // 8 MB
  unsigned short* Wpb  = (unsigned short*)(w + 24 * MB);   // 2 MB
  unsigned short* Wmb  = (unsigned short*)(w + 26 * MB);   // 4 MB
  unsigned short* ctxb = (unsigned short*)(w + 30 * MB);   // 8 MB
  unsigned short* xb   = (unsigned short*)(w + 38 * MB);   // 8 MB

  const int NQ = BB * SS * DD;  // 4M
  cvt_kernel<<<dim3(NQ / 4 / 256), 256, 0, stream>>>(q, qb, NQ / 4);
  cvt_kernel<<<dim3(NQ / 4 / 256), 256, 0, stream>>>(k, kb, NQ / 4);
  cvt_kernel<<<dim3(DD * DD / 4 / 256), 256, 0, stream>>>(W_proj, Wpb, DD * DD / 4);
  cvt_kernel<<<dim3(2 * DD * DD / 4 / 256), 256, 0, stream>>>(W_minus, Wmb, 2 * DD * DD / 4);
  vtrans_kernel<<<dim3(16, BHH), 256, 0, stream>>>(v, vT);

  attn_fused_kernel<<<dim3(16, BHH), 256, 0, stream>>>(qb, kb, vT, scores, mask, c, att, ctxb);
  proj_mfma_kernel<<<dim3(16, 64), 256, 0, stream>>>(ctxb, Wpb, xb);
  minus_mfma_kernel<<<dim3(16, 64), 256, 0, stream>>>(qb, xb, Wmb, y);
  ln_kernel<<<dim3(BB * SS), 256, 0, stream>>>(y, ln_w, ln_b);
}